// Round 20
// baseline (21676.819 us; speedup 1.0000x reference)
//
#include <hip/hip_runtime.h>
#include <stdint.h>

#define T_STEPS 25
#define BATCH   1024
#define IN_F    784
#define HID     4096
#define OUTF    10
// Eigen SINGLE-THREADED gebp blocking (verified bit-exact R11-R19):
// max_kc=288 evened -> kc(784)=264 (264+264+256), kc(4096)=280 (14x280+176).
#define KC_L0   264
#define KC_L1   280
#define KCHUNK  128
#define COLS    256     // columns per slab (per block)
#define NB      4       // batch rows per block (weight reuse factor)

typedef float v2f __attribute__((ext_vector_type(2)));

// ---------------- Threefry-2x32, key = (0, 42), 20 rounds ----------------
__device__ __forceinline__ uint32_t rotl32(uint32_t x, int d) {
    return (x << d) | (x >> (32 - d));
}

__device__ __forceinline__ void threefry2x32_42(uint32_t x0, uint32_t x1,
                                                uint32_t& r0, uint32_t& r1) {
    const uint32_t k0 = 0u, k1 = 42u;
    const uint32_t k2 = k0 ^ k1 ^ 0x1BD11BDAu;
    x0 += k0; x1 += k1;
#define TF_ROUND(r) { x0 += x1; x1 = rotl32(x1, r); x1 ^= x0; }
    TF_ROUND(13) TF_ROUND(15) TF_ROUND(26) TF_ROUND(6)
    x0 += k1; x1 += k2 + 1u;
    TF_ROUND(17) TF_ROUND(29) TF_ROUND(16) TF_ROUND(24)
    x0 += k2; x1 += k0 + 2u;
    TF_ROUND(13) TF_ROUND(15) TF_ROUND(26) TF_ROUND(6)
    x0 += k0; x1 += k1 + 3u;
    TF_ROUND(17) TF_ROUND(29) TF_ROUND(16) TF_ROUND(24)
    x0 += k1; x1 += k2 + 4u;
    TF_ROUND(13) TF_ROUND(15) TF_ROUND(26) TF_ROUND(6)
    x0 += k2; x1 += k0 + 5u;
#undef TF_ROUND
    r0 = x0; r1 = x1;
}

// ---------------- Input spike generation (bitmask, ballot) ----------------
__global__ __launch_bounds__(256) void gen_spikes(const float* __restrict__ x,
                                                  uint64_t* __restrict__ Sin) {
    const int lane = threadIdx.x & 63;
    const int wid  = __builtin_amdgcn_readfirstlane(blockIdx.x * 4 + (threadIdx.x >> 6));
    if (wid >= T_STEPS * BATCH) return;
    const int b = wid % BATCH;

    for (int qw = 0; qw < 16; ++qw) {
        bool pred = false;
        const int f = qw * 64 + lane;
        if (f < IN_F) {
            const uint32_t i = (uint32_t)(wid * IN_F + f);
            uint32_t r0, r1;
            threefry2x32_42(0u, i, r0, r1);
            const uint32_t bits = r0 ^ r1;
            const uint32_t fbits = (bits >> 9) | 0x3f800000u;
            const float u = __uint_as_float(fbits) - 1.0f;
            float p = x[b * IN_F + f];
            p = fminf(fmaxf(p, 0.0f), 1.0f);
            pred = (u < p);
        }
        const uint64_t mask = __ballot((int)pred);
        if (lane == 0) Sin[(long long)wid * 16 + qw] = mask;
    }
}

// ------- Weight transpose+slab-pack: WTp[hb][f][c] = W[hb*256+c][f] -------
// Each element written once; value for (k, col) is bit-identical to the
// verified layout — only the address changes (256-col contiguous slabs).
__global__ __launch_bounds__(256) void transpose_pack(const float* __restrict__ W,
                                                      float* __restrict__ WTp,
                                                      int H, int F) {
    const long long idx = (long long)blockIdx.x * blockDim.x + threadIdx.x;
    const long long tot = (long long)H * F;
    if (idx >= tot) return;
    const long long f = idx / H;
    const long long h = idx % H;
    const long long hb = h >> 8;          // h / 256
    const long long c  = h & 255;         // h % 256
    WTp[(hb * F + f) * COLS + c] = W[h * (long long)F + f];
}

// ---------------- Fused layer: 1 col x 4 batch rows per thread ------------
// Bit-exact to Eigen gebp (verified R11-R19): per (b,col) element,
// S[t] += fbit*w with k flat ascending, folds at global k % KCB == 0 via
// scalar countdown, tail fold, strict-f32 LIF. One weight load per thread
// per k feeds 100 FMAs (4 b x 25 t). Spike tile [k][t][4b] floats: one
// ds_read_b128 = 4 b-values of one t -> two v_pk_fma_f32 (consecutive reg
// pairs, no repack). v2f ops are per-component IEEE — rounding unchanged.
template<int KCB, int KTOT, int IN_STRIDE, int HTOT>
__global__ __launch_bounds__(256, 2) void layer_fmac(
    const uint64_t* __restrict__ Bin,   // [T][B][IN_STRIDE] u64, bit index = k
    const float*    __restrict__ WTp,   // [H/256][KTOT][256] packed slabs
    uint64_t*       __restrict__ Bout)  // [T][B][HTOT/64]
{
    __shared__ alignas(16) float tile[KCHUNK * 100];   // [k][t=25][b=4], 51.2 KB
    const int tid  = threadIdx.x;
    const int lane = tid & 63;
    const int wv   = tid >> 6;
    const int NBG  = BATCH / NB;
    const int bg   = blockIdx.x % NBG;               // hb-major grid
    const int hb   = blockIdx.x / NBG;
    const int b0   = bg * NB;
    const float* __restrict__ Wslab = WTp + (long long)hb * KTOT * COLS;

    v2f S[50], A[50];                   // [t][pair]: S[t*2+p], 4 b = 2 pairs
#pragma unroll
    for (int j = 0; j < 50; ++j) { S[j] = (v2f)0.0f; A[j] = (v2f)0.0f; }

    int nf = KCB;                       // next fold boundary (k+1 == nf)
    const int NCH = (KTOT + KCHUNK - 1) / KCHUNK;
    for (int c = 0; c < NCH; ++c) {
        const int k0 = c * KCHUNK;
        const int kv = (KTOT - k0 < KCHUNK) ? (KTOT - k0) : KCHUNK;
        __syncthreads();                // previous tile fully consumed
        const int NV = kv * 100;        // kv * 25 t * 4 b
        for (int r = 0; r < (NV + 255) / 256; ++r) {
            const int idx = r * 256 + tid;
            if (idx < NV) {
                const int kk  = (idx * 5243) >> 19;  // idx/100, exact < 12800
                const int rem = idx - kk * 100;
                const int t   = rem >> 2;
                const int bb  = rem & 3;
                const int k   = k0 + kk;
                const uint64_t word =
                    Bin[((long long)t * BATCH + (b0 + bb)) * IN_STRIDE + (k >> 6)];
                tile[kk * 100 + rem] = ((word >> (k & 63)) & 1ull) ? 1.0f : 0.0f;
            }
        }
        __syncthreads();

        float w = Wslab[(long long)k0 * COLS + tid];
        for (int kk = 0; kk < kv; ++kk) {
            const int kn = (kk + 1 < kv) ? kk + 1 : kv - 1;   // clamped prefetch
            const float wn = Wslab[(long long)(k0 + kn) * COLS + tid];
            const float* fb = &tile[kk * 100];
            v2f w2; w2.x = w; w2.y = w;
#pragma unroll
            for (int t = 0; t < T_STEPS; ++t) {     // 25 x ds_read_b128
                const float4 f = *(const float4*)(fb + t * 4);
                v2f lo; lo.x = f.x; lo.y = f.y;     // (b0,b1) — consecutive regs
                v2f hi; hi.x = f.z; hi.y = f.w;     // (b2,b3)
                S[t * 2]     = __builtin_elementwise_fma(lo, w2, S[t * 2]);
                S[t * 2 + 1] = __builtin_elementwise_fma(hi, w2, S[t * 2 + 1]);
            }
            if (k0 + kk + 1 == nf) {                // exact KC fold boundary
#pragma unroll
                for (int j = 0; j < 50; ++j) { A[j] = A[j] + S[j]; S[j] = (v2f)0.0f; }
                nf += KCB;
            }
            w = wn;
        }
    }
    if (KTOT % KCB != 0) {
#pragma unroll
        for (int j = 0; j < 50; ++j) A[j] = A[j] + S[j];
    }

    // LIF recursion x4 b, strict f32 separate roundings (verified R11)
#pragma unroll
    for (int bb = 0; bb < NB; ++bb) {
        float m = 0.0f;
#pragma unroll
        for (int t = 0; t < T_STEPS; ++t) {
            const v2f a = A[t * 2 + (bb >> 1)];
            const float ca = (bb & 1) ? a.y : a.x;
            const float reset = (m > 1.0f) ? 1.0f : 0.0f;
            m = __fsub_rn(__fadd_rn(__fmul_rn(0.9f, m), ca), reset);
            const uint64_t mask = __ballot((int)(m > 1.0f));
            if (lane == 0)
                Bout[((long long)t * BATCH + (b0 + bb)) * (HTOT / 64) + hb * 4 + wv] = mask;
        }
    }
}

// ---------------- Output layer (H=10): counts, blocked f32 (kc=280) -------
__global__ __launch_bounds__(256) void layer_out(const uint64_t* __restrict__ S1,
                                                 const float* __restrict__ W2,
                                                 float* __restrict__ out) {
    const int idx = blockIdx.x * blockDim.x + threadIdx.x;
    const int b = idx >> 4;   // 16 threads per batch row (10 used)
    const int o = idx & 15;
    if (b >= BATCH) return;

    float m = 0.0f;
    float cnt = 0.0f;
    for (int t = 0; t < T_STEPS; ++t) {
        float acc = 0.0f;
        float S = 0.0f;
        if (o < OUTF) {
            for (int qw = 0; qw < 64; ++qw) {
                const uint64_t sw = S1[((long long)t * BATCH + b) * 64 + qw];
                const float* wrow = W2 + (long long)o * HID + qw * 64;
#pragma unroll
                for (int fb = 0; fb < 64; ++fb) {
                    S = __fadd_rn(S, ((sw >> fb) & 1ull) ? wrow[fb] : 0.0f);
                    if (((qw * 64 + fb + 1) % KC_L1) == 0) {
                        acc = __fadd_rn(acc, S);
                        S = 0.0f;
                    }
                }
            }
            if (HID % KC_L1 != 0) acc = __fadd_rn(acc, S);
        }
        const float reset = (m > 1.0f) ? 1.0f : 0.0f;
        m = __fsub_rn(__fadd_rn(__fmul_rn(0.9f, m), acc), reset);
        if (m > 1.0f) cnt += 1.0f;
    }
    if (o < OUTF) out[b * OUTF + o] = cnt;
}

// ---------------- Launch ----------------
extern "C" void kernel_launch(void* const* d_in, const int* in_sizes, int n_in,
                              void* d_out, int out_size, void* d_ws, size_t ws_size,
                              hipStream_t stream) {
    const float* x  = (const float*)d_in[0];
    const float* W0 = (const float*)d_in[1];
    const float* W1 = (const float*)d_in[2];
    const float* W2 = (const float*)d_in[3];
    float* out = (float*)d_out;

    char* ws = (char*)d_ws;
    size_t off = 0;
    float* WT0 = (float*)(ws + off); off += (size_t)IN_F * HID * sizeof(float);   // 12.8 MB
    float* WT1 = (float*)(ws + off); off += (size_t)HID * HID * sizeof(float);    // 64 MB
    uint64_t* Sin = (uint64_t*)(ws + off); off += (size_t)T_STEPS * BATCH * 16 * 8; // 3.3 MB
    uint64_t* S0  = (uint64_t*)(ws + off); off += (size_t)T_STEPS * BATCH * 64 * 8; // 13.1 MB
    uint64_t* S1  = (uint64_t*)(ws + off); off += (size_t)T_STEPS * BATCH * 64 * 8; // 13.1 MB
    (void)off; (void)ws_size; (void)in_sizes; (void)n_in; (void)out_size;

    // 1) transpose + slab-pack weights (256-col contiguous slabs)
    {
        long long tot0 = (long long)HID * IN_F;
        transpose_pack<<<(int)((tot0 + 255) / 256), 256, 0, stream>>>(W0, WT0, HID, IN_F);
        long long tot1 = (long long)HID * HID;
        transpose_pack<<<(int)((tot1 + 255) / 256), 256, 0, stream>>>(W1, WT1, HID, HID);
    }
    // 2) Poisson spike raster via threefry (partitionable, XOR readout)
    gen_spikes<<<(T_STEPS * BATCH) / 4, 256, 0, stream>>>(x, Sin);
    // 3) layer 0: 784 -> 4096, kc=264
    layer_fmac<KC_L0, IN_F, 16, HID>
        <<<(HID / COLS) * (BATCH / NB), 256, 0, stream>>>(Sin, WT0, S0);
    // 4) layer 1: 4096 -> 4096, kc=280
    layer_fmac<KC_L1, HID, 64, HID>
        <<<(HID / COLS) * (BATCH / NB), 256, 0, stream>>>(S0, WT1, S1);
    // 5) layer 2: 4096 -> 10, kc=280, spike counts
    layer_out<<<BATCH * 16 / 256, 256, 0, stream>>>(S1, W2, out);
}